// Round 4
// baseline (722442.773 us; speedup 1.0000x reference)
//
#include <hip/hip_runtime.h>
#include <hip/hip_bf16.h>

// ImplicitRNNCell, R11: R10's L2-local exchange (plain stores + sc0 loads),
// hardened after R10's no-output failure (possible hang):
//   - control skeleton restored to R9's PROVEN form: wave0-only poll +
//     __syncthreads broadcast, in both modes.
//   - fenceless poll escalates to agent-scope loads after ~32K spins
//     (hang-escape: degrades to slow/failing instead of wedging).
//   - FEN fallback: release-agent fence (L2 writeback) before every agent
//     flag store + acquire after poll -> correct cross-XCD even with plain
//     data stores. Engaged on any XCD-check anomaly.
// Theory (R9 counters): relaxed agent atomics bypass the XCD-local L2
// (WRITE_SIZE 625MB, round latency 4.1us unchanged without fences) -> every
// sync leg was an LLC round-trip. Plain stores land in the shared local L2
// (L1 write-through; vmcnt(0) drain at __syncthreads = completed-in-L2);
// sc0 loads bypass L1 and hit that L2. Same-XCD placement verified at
// runtime via s_getreg(XCC_ID) (group-uniform + neighbor-differs).
// Rounds/t = 3 (X1, X2, H); X3 local; h = consumer-side sum of 8 f32
// partials (Hpart single-buffered; ordered by the X1-flag round).

typedef __bf16 bf16x8 __attribute__((ext_vector_type(8)));
typedef __bf16 bf16x4 __attribute__((ext_vector_type(4)));
typedef float  f32x4  __attribute__((ext_vector_type(4)));
typedef unsigned int       u32;
typedef unsigned int       u32x4 __attribute__((ext_vector_type(4)));
typedef unsigned long long u64;

#define B_SZ   512
#define SEQ    64
#define IN_DIM 128
#define HID    256
#define NIMP   512
#define PDIM   384
#define BC     16
#define GW     8
#define NEV    4    // idx0=X1, idx1=X2, idx2=H, idx3=init/XCD-id
#define UPAD   392
#define XPAD   520
#define X3PAD  72

__device__ __forceinline__ unsigned short bfb(float f) {
    __bf16 b = (__bf16)f;
    return __builtin_bit_cast(unsigned short, b);
}
// plain store (wg-scope atomic => global_store, no sc bits; lands in local L2)
__device__ __forceinline__ void stp64(u64* p, u64 v) {
    __hip_atomic_store(p, v, __ATOMIC_RELAXED, __HIP_MEMORY_SCOPE_WORKGROUP);
}
__device__ __forceinline__ u32 ld32sys(const u32* p) {
    return __hip_atomic_load(p, __ATOMIC_RELAXED, __HIP_MEMORY_SCOPE_SYSTEM);
}
__device__ __forceinline__ u64 packf2(float a, float b) {
    return ((u64)__builtin_bit_cast(u32, b) << 32) | __builtin_bit_cast(u32, a);
}
// sc0 = L1-bypass, L2-served loads. waitcnt stays inside the asm block with
// the outputs so consumers are ordered by data deps (guide rule #18).
__device__ __forceinline__ u32 ld32_sc0(const u32* p) {
    u32 r;
    asm volatile("global_load_dword %0, %1, off sc0\n\t"
                 "s_waitcnt vmcnt(0)"
                 : "=&v"(r) : "v"(p) : "memory");
    return r;
}
__device__ __forceinline__ void ld2x16_sc0(const u32* p, u32x4& a, u32x4& b) {
    asm volatile("global_load_dwordx4 %0, %2, off sc0\n\t"
                 "global_load_dwordx4 %1, %2, off offset:512 sc0\n\t"
                 "s_waitcnt vmcnt(0)"
                 : "=&v"(a), "=&v"(b) : "v"(p) : "memory");
}
__device__ __forceinline__ void ld8x16_sc0(const float* p0, const float* p1,
                                           const float* p2, const float* p3,
                                           f32x4& a0, f32x4& a1, f32x4& b0, f32x4& b1,
                                           f32x4& c0, f32x4& c1, f32x4& d0, f32x4& d1) {
    asm volatile(
        "global_load_dwordx4 %0, %8, off sc0\n\t"
        "global_load_dwordx4 %1, %8, off offset:16 sc0\n\t"
        "global_load_dwordx4 %2, %9, off sc0\n\t"
        "global_load_dwordx4 %3, %9, off offset:16 sc0\n\t"
        "global_load_dwordx4 %4, %10, off sc0\n\t"
        "global_load_dwordx4 %5, %10, off offset:16 sc0\n\t"
        "global_load_dwordx4 %6, %11, off sc0\n\t"
        "global_load_dwordx4 %7, %11, off offset:16 sc0\n\t"
        "s_waitcnt vmcnt(0)"
        : "=&v"(a0), "=&v"(a1), "=&v"(b0), "=&v"(b1),
          "=&v"(c0), "=&v"(c1), "=&v"(d0), "=&v"(d1)
        : "v"(p0), "v"(p1), "v"(p2), "v"(p3)
        : "memory");
}

// wave0 only: poll 8 per-WG flags (64B apart) until all == tok.
// fen=false: sc0 poll (local L2); escalates to agent loads after ~32K spins
// (hang-escape). fen=true: agent poll + ONE acquire fence (R7-proven).
__device__ __forceinline__ void gw(const u32* f, u32 tok, int lane, bool fen) {
    int spins = 0;
    while (true) {
        u32 v;
        if (fen || spins > 32768)
            v = (lane < GW) ? __hip_atomic_load(f + lane * 16, __ATOMIC_RELAXED,
                                                __HIP_MEMORY_SCOPE_AGENT)
                            : tok;
        else
            v = (lane < GW) ? ld32_sc0(f + lane * 16) : tok;
        if (__ballot(v == tok) == ~0ull) break;
        __builtin_amdgcn_s_sleep(1);
        ++spins;
    }
    if (fen) __builtin_amdgcn_fence(__ATOMIC_ACQUIRE, "agent");
    else     asm volatile("" ::: "memory");
}

// producer side: post token. fen=true: release-agent fence first (emits the
// L2 writeback on multi-XCD gfx9) so plain data stores are LLC-visible.
__device__ __forceinline__ void post_flag(u32* slot, u32 tok, bool fen) {
    if (fen) {
        __builtin_amdgcn_fence(__ATOMIC_RELEASE, "agent");
        __hip_atomic_store(slot, tok, __ATOMIC_RELAXED, __HIP_MEMORY_SCOPE_AGENT);
    } else {
        __hip_atomic_store(slot, tok, __ATOMIC_RELAXED, __HIP_MEMORY_SCOPE_WORKGROUP);
    }
}

__global__ void convert_plain(const float* __restrict__ src,
                              __bf16* __restrict__ dst, int n4) {
    int i = blockIdx.x * blockDim.x + threadIdx.x;
    if (i >= n4) return;
    float4 v = reinterpret_cast<const float4*>(src)[i];
    bf16x4 o;
    o[0] = (__bf16)v.x; o[1] = (__bf16)v.y; o[2] = (__bf16)v.z; o[3] = (__bf16)v.w;
    reinterpret_cast<bf16x4*>(dst)[i] = o;
}

__global__ void convert_split(const float* __restrict__ src,
                              __bf16* __restrict__ hi, __bf16* __restrict__ lo,
                              int n4) {
    int i = blockIdx.x * blockDim.x + threadIdx.x;
    if (i >= n4) return;
    float4 v = reinterpret_cast<const float4*>(src)[i];
    float f[4] = {v.x, v.y, v.z, v.w};
    bf16x4 h, l;
#pragma unroll
    for (int e = 0; e < 4; ++e) {
        __bf16 hh = (__bf16)f[e];
        h[e] = hh;
        l[e] = (__bf16)(f[e] - (float)hh);
    }
    reinterpret_cast<bf16x4*>(hi)[i] = h;
    reinterpret_cast<bf16x4*>(lo)[i] = l;
}

__global__ void zero_u32(u32* __restrict__ p, int n) {
    int i = blockIdx.x * blockDim.x + threadIdx.x;
    if (i < n) p[i] = 0;
}

__global__ __launch_bounds__(512, 2)
void rnn_kernel(const float* __restrict__ x,
                const __bf16* __restrict__ Abf,
                const __bf16* __restrict__ Bhi, const __bf16* __restrict__ Blo,
                const __bf16* __restrict__ Chi, const __bf16* __restrict__ Clo,
                const __bf16* __restrict__ Dhi, const __bf16* __restrict__ Dlo,
                float* __restrict__ out,
                u32* __restrict__ flags,   // [32][NEV][8*16]
                u32* __restrict__ Xex,     // [2][32][16][256] packed row-pairs (hi)
                float* __restrict__ Hpart) {// [32][8][16][256] f32 partial h
    __shared__ __bf16 Xhi[BC][XPAD];
    __shared__ __bf16 Xlo3[BC][X3PAD];   // X3 lo, local staging only (64 k)
    __shared__ __bf16 u_hi[BC][UPAD];
    __shared__ __bf16 u_lo[BC][UPAD];
    __shared__ f32x4  red4[10][64];      // 0..3: bu / A-it ; 4..9: D-part
    __shared__ float  dsum[32][16];      // D@u rows [32*sub,+32)
    __shared__ int    s_nofence;

    const int tid  = threadIdx.x;
    const int wave = tid >> 6;
    const int lane = tid & 63;
    const int quad = lane >> 4;
    const int l16  = lane & 15;
    const int g    = blockIdx.x & 31;   // blocks {g, g+32k}: same XCD under %8 map
    const int sub  = blockIdx.x >> 5;   // 0..7
    const int R0   = sub * 64;
    const int H0   = sub * 32;
    const int b0   = g * BC;
    const int m    = wave & 3;
    const int kh   = wave >> 2;
    const int m2   = wave & 1;
    const int kh4  = wave >> 1;

    // ---- preload weight fragments ----
    bf16x8 aF[8], bFh[6], bFl[6], cFh[2][2], cFl[2][2], dFh[3], dFl[3];
    {
        const int arow = R0 + m * 16 + l16;
#pragma unroll
        for (int s = 0; s < 8; ++s)
            aF[s] = *reinterpret_cast<const bf16x8*>(
                &Abf[arow * NIMP + (kh * 8 + s) * 32 + quad * 8]);
#pragma unroll
        for (int s = 0; s < 6; ++s) {
            const int o = arow * PDIM + (kh * 6 + s) * 32 + quad * 8;
            bFh[s] = *reinterpret_cast<const bf16x8*>(&Bhi[o]);
            bFl[s] = *reinterpret_cast<const bf16x8*>(&Blo[o]);
        }
        // partial-h: wave w owns h-rows [32w, +32), K-slice = own X rows [R0,+64)
#pragma unroll
        for (int tl = 0; tl < 2; ++tl)
#pragma unroll
        for (int s = 0; s < 2; ++s) {
            const int o = (32 * wave + tl * 16 + l16) * NIMP + R0 + s * 32 + quad * 8;
            cFh[tl][s] = *reinterpret_cast<const bf16x8*>(&Chi[o]);
            cFl[tl][s] = *reinterpret_cast<const bf16x8*>(&Clo[o]);
        }
        const int hrow = H0 + m2 * 16 + l16;
#pragma unroll
        for (int s = 0; s < 3; ++s) {
            const int o = hrow * PDIM + (kh4 * 3 + s) * 32 + quad * 8;
            dFh[s] = *reinterpret_cast<const bf16x8*>(&Dhi[o]);
            dFl[s] = *reinterpret_cast<const bf16x8*>(&Dlo[o]);
        }
    }

    u32* const fg   = flags + g * (NEV * GW * 16);
    const int xcol  = tid >> 5;   // 0..15
    const int xseg  = tid & 31;   // 0..31

    // ---- init: runtime XCD-uniformity check (decides fenceless mode) ----
    {
        u32 myid = __builtin_amdgcn_s_getreg((31u << 11) | 20u); // hwreg(XCC_ID,0,32)
        if (tid == 0)
            __hip_atomic_store(fg + 3 * (GW * 16) + sub * 16, 0x100u | (myid & 0xffu),
                               __ATOMIC_RELAXED, __HIP_MEMORY_SCOPE_SYSTEM);
        if (wave == 0) {
            u32 v = 0x100u;
            while (true) {
                v = (lane < GW) ? ld32sys(fg + 3 * (GW * 16) + lane * 16) : 0x100u;
                if (__ballot((v & 0x100u) != 0u) == ~0ull) break;
                __builtin_amdgcn_s_sleep(8);
            }
            u32 ref = __shfl((int)v, 0);
            bool same = (lane < GW) ? (v == ref) : true;
            bool allsame = (__ballot(same) == ~0ull);
            u32 nb = 0;
            if (lane == 0) {
                const u32* ns = flags + (size_t)((g + 1) & 31) * (NEV * GW * 16)
                              + 3 * (GW * 16);
                while (((nb = ld32sys(ns)) & 0x100u) == 0u)
                    __builtin_amdgcn_s_sleep(8);
            }
            nb = (u32)__shfl((int)nb, 0);
            if (lane == 0)
                s_nofence = (allsame && ((nb & 0xffu) != (ref & 0xffu))) ? 1 : 0;
        }
        __syncthreads();
    }
    const bool FEN = (s_nofence == 0);   // wave-uniform

    // consumer-side: read 8 f32 partials via sc0 (L2), sum -> hv[8]
    auto read_h_sum = [&](float* hv) {
        const float* base = Hpart + ((size_t)(g * 8 * 16) + xcol) * 256 + xseg * 8;
        f32x4 a0, a1, b0v, b1v, c0, c1, d0v, d1v;
        ld8x16_sc0(base, base + 4096, base + 8192, base + 12288,
                   a0, a1, b0v, b1v, c0, c1, d0v, d1v);
        f32x4 sA = a0 + b0v + c0 + d0v;
        f32x4 sB = a1 + b1v + c1 + d1v;
        ld8x16_sc0(base + 16384, base + 20480, base + 24576, base + 28672,
                   a0, a1, b0v, b1v, c0, c1, d0v, d1v);
        sA += a0 + b0v + c0 + d0v;
        sB += a1 + b1v + c1 + d1v;
        hv[0] = sA[0]; hv[1] = sA[1]; hv[2] = sA[2]; hv[3] = sA[3];
        hv[4] = sB[0]; hv[5] = sB[1]; hv[6] = sB[2]; hv[7] = sB[3];
    };

    for (int t = 0; t < SEQ; ++t) {
        const u32 tok = (u32)(t + 1);
        // ---- stage x-part of u ----
        {
            const int p4 = xseg << 2;
            float4 v = *reinterpret_cast<const float4*>(
                &x[((size_t)(b0 + xcol) * SEQ + t) * IN_DIM + p4]);
            float f[4] = {v.x, v.y, v.z, v.w};
            bf16x4 h, l;
#pragma unroll
            for (int e = 0; e < 4; ++e) {
                __bf16 hh = (__bf16)f[e];
                h[e] = hh;
                l[e] = (__bf16)(f[e] - (float)hh);
            }
            *reinterpret_cast<bf16x4*>(&u_hi[xcol][p4]) = h;
            *reinterpret_cast<bf16x4*>(&u_lo[xcol][p4]) = l;
        }
        if (t == 0) {
            bf16x8 z = {};
            *reinterpret_cast<bf16x8*>(&u_hi[xcol][IN_DIM + xseg * 8]) = z;
            *reinterpret_cast<bf16x8*>(&u_lo[xcol][IN_DIM + xseg * 8]) = z;
        } else {
            if (wave == 0) gw(fg + 2 * (GW * 16), (u32)t, lane, FEN);
            __syncthreads();
            float hv[8];
            read_h_sum(hv);
            bf16x8 hh, hl;
#pragma unroll
            for (int e = 0; e < 8; ++e) {
                __bf16 q = (__bf16)hv[e];
                hh[e] = q;
                hl[e] = (__bf16)(hv[e] - (float)q);
            }
            *reinterpret_cast<bf16x8*>(&u_hi[xcol][IN_DIM + xseg * 8]) = hh;
            *reinterpret_cast<bf16x8*>(&u_lo[xcol][IN_DIM + xseg * 8]) = hl;
            if ((xseg >> 2) == sub) {
                float4 o0 = {hv[0], hv[1], hv[2], hv[3]};
                float4 o1 = {hv[4], hv[5], hv[6], hv[7]};
                size_t ob = ((size_t)(b0 + xcol) * SEQ + (t - 1)) * HID + xseg * 8;
                *reinterpret_cast<float4*>(&out[ob])     = o0;
                *reinterpret_cast<float4*>(&out[ob + 4]) = o1;
            }
        }
        __syncthreads();

        // ---- bu = Bmat @ u (split, K-halved across wave pairs) ----
        f32x4 acc = {0.f, 0.f, 0.f, 0.f};
#pragma unroll
        for (int s = 0; s < 6; ++s) {
            const int k0 = (kh * 6 + s) * 32 + quad * 8;
            bf16x8 uh = *reinterpret_cast<const bf16x8*>(&u_hi[l16][k0]);
            bf16x8 ul = *reinterpret_cast<const bf16x8*>(&u_lo[l16][k0]);
            acc = __builtin_amdgcn_mfma_f32_16x16x32_bf16(bFh[s], uh, acc, 0, 0, 0);
            acc = __builtin_amdgcn_mfma_f32_16x16x32_bf16(bFh[s], ul, acc, 0, 0, 0);
            acc = __builtin_amdgcn_mfma_f32_16x16x32_bf16(bFl[s], uh, acc, 0, 0, 0);
        }
        if (kh == 1) red4[m][lane] = acc;
        __syncthreads();
        f32x4 bu_acc = acc;
        if (kh == 0) bu_acc = acc + red4[m][lane];

        // ---- broadcast own X chunk, read back all 512 rows (R9 skeleton) ----
        auto xexchange = [&](int itx, const f32x4& tot) {
            const int buf = itx & 1;
            if (kh == 0) {
                float r0f = fmaxf(tot[0], 0.f), r1f = fmaxf(tot[1], 0.f);
                float r2f = fmaxf(tot[2], 0.f), r3f = fmaxf(tot[3], 0.f);
                u32 d0 = (u32)bfb(r0f) | ((u32)bfb(r1f) << 16);
                u32 d1 = (u32)bfb(r2f) | ((u32)bfb(r3f) << 16);
                const int rp = (R0 + m * 16 + quad * 4) >> 1;
                stp64(reinterpret_cast<u64*>(
                          Xex + (((size_t)buf * 32 + g) * 16 + l16) * 256 + rp),
                      ((u64)d1 << 32) | d0);
            }
            __syncthreads();  // every wave drains vmcnt(0) -> stores in L2
            {
                u32* f = fg + itx * (GW * 16);
                if (wave == 0) {
                    if (lane == 0) post_flag(f + sub * 16, tok, FEN);
                    gw(f, tok, lane, FEN);
                }
            }
            __syncthreads();
            {   // read back full X (hi) via sc0 (L2)
                const u32* src = Xex + (((size_t)buf * 32 + g) * 16 + xcol) * 256
                               + xseg * 4;
                u32x4 qa, qb;
                ld2x16_sc0(src, qa, qb);
                union { u32x4 q; bf16x8 v; } cA, cB;
                cA.q = qa; cB.q = qb;
                *reinterpret_cast<bf16x8*>(&Xhi[xcol][xseg * 8])       = cA.v;
                *reinterpret_cast<bf16x8*>(&Xhi[xcol][256 + xseg * 8]) = cB.v;
            }
            __syncthreads();
        };

        // ---- X1 = relu(bu), round 0 ----
        xexchange(0, bu_acc);

        // ---- it=2: X2 = relu(A @ X1 + bu), round 1 ----
        {
            f32x4 p;
            if (kh == 0) p = bu_acc;
            else { p[0] = 0.f; p[1] = 0.f; p[2] = 0.f; p[3] = 0.f; }
#pragma unroll
            for (int s = 0; s < 8; ++s) {
                const int k0 = (kh * 8 + s) * 32 + quad * 8;
                bf16x8 xF = *reinterpret_cast<const bf16x8*>(&Xhi[l16][k0]);
                p = __builtin_amdgcn_mfma_f32_16x16x32_bf16(aF[s], xF, p, 0, 0, 0);
            }
            if (kh == 1) red4[m][lane] = p;
            __syncthreads();
            f32x4 tot = p;
            if (kh == 0) tot = p + red4[m][lane];
            xexchange(1, tot);
        }

        // ---- it=3: X3 = relu(A @ X2 + bu) stays LOCAL (f32 -> hi/lo LDS) ----
        {
            f32x4 p;
            if (kh == 0) p = bu_acc;
            else { p[0] = 0.f; p[1] = 0.f; p[2] = 0.f; p[3] = 0.f; }
#pragma unroll
            for (int s = 0; s < 8; ++s) {
                const int k0 = (kh * 8 + s) * 32 + quad * 8;
                bf16x8 xF = *reinterpret_cast<const bf16x8*>(&Xhi[l16][k0]);
                p = __builtin_amdgcn_mfma_f32_16x16x32_bf16(aF[s], xF, p, 0, 0, 0);
            }
            if (kh == 1) red4[m][lane] = p;
            __syncthreads();                               // sync#1
            if (kh == 0) {
                f32x4 tot = p + red4[m][lane];
                bf16x4 xh, xl;
#pragma unroll
                for (int j = 0; j < 4; ++j) {
                    float r = fmaxf(tot[j], 0.f);
                    __bf16 hh = (__bf16)r;
                    xh[j] = hh;
                    xl[j] = (__bf16)(r - (float)hh);
                }
                *reinterpret_cast<bf16x4*>(&Xhi[l16][m * 16 + quad * 4])  = xh;
                *reinterpret_cast<bf16x4*>(&Xlo3[l16][m * 16 + quad * 4]) = xl;
            }
        }

        // ---- partial h: D@u (own 32 rows, K-quartered) + C_slice @ X3 ----
        {
            f32x4 hp = {0.f, 0.f, 0.f, 0.f};
#pragma unroll
            for (int s = 0; s < 3; ++s) {
                const int k0 = (kh4 * 3 + s) * 32 + quad * 8;
                bf16x8 uh = *reinterpret_cast<const bf16x8*>(&u_hi[l16][k0]);
                bf16x8 ul = *reinterpret_cast<const bf16x8*>(&u_lo[l16][k0]);
                hp = __builtin_amdgcn_mfma_f32_16x16x32_bf16(dFh[s], uh, hp, 0, 0, 0);
                hp = __builtin_amdgcn_mfma_f32_16x16x32_bf16(dFh[s], ul, hp, 0, 0, 0);
                hp = __builtin_amdgcn_mfma_f32_16x16x32_bf16(dFl[s], uh, hp, 0, 0, 0);
            }
            if (kh4 > 0) red4[4 + m2 * 3 + (kh4 - 1)][lane] = hp;
            __syncthreads();                               // sync#2 (X3 staged too)
            if (kh4 == 0) {
                f32x4 dt = hp + red4[4 + m2 * 3][lane] + red4[4 + m2 * 3 + 1][lane]
                              + red4[4 + m2 * 3 + 2][lane];
#pragma unroll
                for (int j = 0; j < 4; ++j)
                    dsum[m2 * 16 + quad * 4 + j][l16] = dt[j];
            }
            // C-part: wave w -> h-rows [32w,+32), K = own 64 X rows
            f32x4 ph0 = {0.f, 0.f, 0.f, 0.f}, ph1 = {0.f, 0.f, 0.f, 0.f};
#pragma unroll
            for (int s = 0; s < 2; ++s) {
                const int k0 = s * 32 + quad * 8;
                bf16x8 xh = *reinterpret_cast<const bf16x8*>(&Xhi[l16][k0]);
                bf16x8 xl = *reinterpret_cast<const bf16x8*>(&Xlo3[l16][k0]);
                ph0 = __builtin_amdgcn_mfma_f32_16x16x32_bf16(cFh[0][s], xh, ph0, 0, 0, 0);
                ph0 = __builtin_amdgcn_mfma_f32_16x16x32_bf16(cFh[0][s], xl, ph0, 0, 0, 0);
                ph0 = __builtin_amdgcn_mfma_f32_16x16x32_bf16(cFl[0][s], xh, ph0, 0, 0, 0);
                ph1 = __builtin_amdgcn_mfma_f32_16x16x32_bf16(cFh[1][s], xh, ph1, 0, 0, 0);
                ph1 = __builtin_amdgcn_mfma_f32_16x16x32_bf16(cFh[1][s], xl, ph1, 0, 0, 0);
                ph1 = __builtin_amdgcn_mfma_f32_16x16x32_bf16(cFl[1][s], xh, ph1, 0, 0, 0);
            }
            __syncthreads();                               // sync#3 (dsum visible)
            if (wave == sub) {
#pragma unroll
                for (int j = 0; j < 4; ++j) {
                    ph0[j] += dsum[quad * 4 + j][l16];
                    ph1[j] += dsum[16 + quad * 4 + j][l16];
                }
            }
            // store f32 partial: Hpart[g][sub][col l16][row 32*wave + ...]
            u64* hb = reinterpret_cast<u64*>(
                Hpart + (((size_t)g * 8 + sub) * 16 + l16) * 256
                      + 32 * wave + quad * 4);
            stp64(hb,     packf2(ph0[0], ph0[1]));
            stp64(hb + 1, packf2(ph0[2], ph0[3]));
            stp64(hb + 8, packf2(ph1[0], ph1[1]));
            stp64(hb + 9, packf2(ph1[2], ph1[3]));
        }
        __syncthreads();  // drain Hpart stores (vmcnt(0) per wave)
        if (tid == 0) post_flag(fg + 2 * (GW * 16) + sub * 16, tok, FEN);
        // waiters poll at the start of timestep t+1
    }

    // ---- tail: h(SEQ-1) -> out[SEQ-1] + h_last ----
    {
        if (wave == 0) gw(fg + 2 * (GW * 16), (u32)SEQ, lane, FEN);
        __syncthreads();
        float hv[8];
        read_h_sum(hv);
        if ((xseg >> 2) == sub) {
            float4 o0 = {hv[0], hv[1], hv[2], hv[3]};
            float4 o1 = {hv[4], hv[5], hv[6], hv[7]};
            size_t ob = ((size_t)(b0 + xcol) * SEQ + (SEQ - 1)) * HID + xseg * 8;
            *reinterpret_cast<float4*>(&out[ob])     = o0;
            *reinterpret_cast<float4*>(&out[ob + 4]) = o1;
            size_t hb2 = (size_t)B_SZ * SEQ * HID + (size_t)(b0 + xcol) * HID + xseg * 8;
            *reinterpret_cast<float4*>(&out[hb2])     = o0;
            *reinterpret_cast<float4*>(&out[hb2 + 4]) = o1;
        }
    }
}

extern "C" void kernel_launch(void* const* d_in, const int* in_sizes, int n_in,
                              void* d_out, int out_size, void* d_ws, size_t ws_size,
                              hipStream_t stream) {
    const float* x  = (const float*)d_in[0];
    const float* A  = (const float*)d_in[1];
    const float* Bm = (const float*)d_in[2];
    const float* C  = (const float*)d_in[3];
    const float* D  = (const float*)d_in[4];
    float* out = (float*)d_out;

    char* ws = (char*)d_ws;
    __bf16* Abf = (__bf16*)(ws);               // 524288
    __bf16* Bhi = (__bf16*)(ws + 524288);      // 393216
    __bf16* Blo = (__bf16*)(ws + 917504);
    __bf16* Chi = (__bf16*)(ws + 1310720);     // 262144
    __bf16* Clo = (__bf16*)(ws + 1572864);
    __bf16* Dhi = (__bf16*)(ws + 1835008);     // 196608
    __bf16* Dlo = (__bf16*)(ws + 2031616);
    u32* flags  = (u32*)(ws + 2228224);        // 32*4*8*16*4 = 65536
    u32* Xex    = (u32*)(ws + 2293760);        // 1048576
    float* Hpart= (float*)(ws + 3342336);      // 32*8*16*256*4 = 4194304 -> 7536640

    convert_plain<<<256, 256, 0, stream>>>(A, Abf, 262144 / 4);
    convert_split<<<192, 256, 0, stream>>>(Bm, Bhi, Blo, 196608 / 4);
    convert_split<<<128, 256, 0, stream>>>(C, Chi, Clo, 131072 / 4);
    convert_split<<<96, 256, 0, stream>>>(D, Dhi, Dlo, 98304 / 4);
    zero_u32<<<64, 256, 0, stream>>>(flags, 32 * NEV * GW * 16);

    rnn_kernel<<<256, 512, 0, stream>>>(x, Abf, Bhi, Blo, Chi, Clo, Dhi, Dlo,
                                        out, flags, Xex, Hpart);
}

// Round 5
// 522.977 us; speedup vs baseline: 1381.4051x; 1381.4051x over previous
//
#include <hip/hip_runtime.h>
#include <hip/hip_bf16.h>

// ImplicitRNNCell, R12: split the exchange by coherence need.
// R11 post-mortem (722ms, passed, absmax 0.25): fenceless engaged; sc0 FLAG
// poll never saw tokens (flag lines pinned hot in L1 by the spin -> served
// stale forever); every round waited out the 32K-spin escalation, whose
// agent load saw the flag immediately. Meanwhile plain data stores + sc0
// data readbacks were CORRECT all run (data lines evicted from L1 between
// rounds by ~100KB/round streaming -> refetched fresh from L2).
// => R12: data legs stay L2-local (plain stores, sc0 batched readbacks —
// both R11-proven); FLAGS go through the agent path (agent store post,
// agent load poll — R7/R9/R11-escalation-proven prompt). One LLC RT per
// round instead of every leg (R9's 4.1us/round).
// FEN fallback (cross-XCD anomaly): release-agent fence (L2 writeback)
// before flag post + acquire-agent fence after poll — R7-proven structure.
// Rounds/t = 3 (X1, X2, H); X3 local; h = consumer-side sum of 8 f32
// partials (Hpart single-buffered; ordered by the X1-flag round).

typedef __bf16 bf16x8 __attribute__((ext_vector_type(8)));
typedef __bf16 bf16x4 __attribute__((ext_vector_type(4)));
typedef float  f32x4  __attribute__((ext_vector_type(4)));
typedef unsigned int       u32;
typedef unsigned int       u32x4 __attribute__((ext_vector_type(4)));
typedef unsigned long long u64;

#define B_SZ   512
#define SEQ    64
#define IN_DIM 128
#define HID    256
#define NIMP   512
#define PDIM   384
#define BC     16
#define GW     8
#define NEV    4    // idx0=X1, idx1=X2, idx2=H, idx3=init/XCD-id
#define UPAD   392
#define XPAD   520
#define X3PAD  72

__device__ __forceinline__ unsigned short bfb(float f) {
    __bf16 b = (__bf16)f;
    return __builtin_bit_cast(unsigned short, b);
}
// plain store (wg-scope atomic => global_store, no sc bits; lands in local L2
// via write-through L1; vmcnt(0) at __syncthreads = completed-in-L2)
__device__ __forceinline__ void stp64(u64* p, u64 v) {
    __hip_atomic_store(p, v, __ATOMIC_RELAXED, __HIP_MEMORY_SCOPE_WORKGROUP);
}
__device__ __forceinline__ u32 ld32sys(const u32* p) {
    return __hip_atomic_load(p, __ATOMIC_RELAXED, __HIP_MEMORY_SCOPE_SYSTEM);
}
__device__ __forceinline__ u64 packf2(float a, float b) {
    return ((u64)__builtin_bit_cast(u32, b) << 32) | __builtin_bit_cast(u32, a);
}
// sc0 batched readbacks: fresh because data lines are evicted from L1
// between rounds (proven R11: absmax 0.25 over 62 steps). waitcnt inside
// the asm block with the outputs (guide rule #18).
__device__ __forceinline__ void ld2x16_sc0(const u32* p, u32x4& a, u32x4& b) {
    asm volatile("global_load_dwordx4 %0, %2, off sc0\n\t"
                 "global_load_dwordx4 %1, %2, off offset:512 sc0\n\t"
                 "s_waitcnt vmcnt(0)"
                 : "=&v"(a), "=&v"(b) : "v"(p) : "memory");
}
__device__ __forceinline__ void ld8x16_sc0(const float* p0, const float* p1,
                                           const float* p2, const float* p3,
                                           f32x4& a0, f32x4& a1, f32x4& b0, f32x4& b1,
                                           f32x4& c0, f32x4& c1, f32x4& d0, f32x4& d1) {
    asm volatile(
        "global_load_dwordx4 %0, %8, off sc0\n\t"
        "global_load_dwordx4 %1, %8, off offset:16 sc0\n\t"
        "global_load_dwordx4 %2, %9, off sc0\n\t"
        "global_load_dwordx4 %3, %9, off offset:16 sc0\n\t"
        "global_load_dwordx4 %4, %10, off sc0\n\t"
        "global_load_dwordx4 %5, %10, off offset:16 sc0\n\t"
        "global_load_dwordx4 %6, %11, off sc0\n\t"
        "global_load_dwordx4 %7, %11, off offset:16 sc0\n\t"
        "s_waitcnt vmcnt(0)"
        : "=&v"(a0), "=&v"(a1), "=&v"(b0), "=&v"(b1),
          "=&v"(c0), "=&v"(c1), "=&v"(d0), "=&v"(d1)
        : "v"(p0), "v"(p1), "v"(p2), "v"(p3)
        : "memory");
}

// wave0 only: poll 8 per-WG flags (64B apart) with AGENT loads (always
// coherence-fresh; R11's proven escape path). Acquire fence only in FEN.
__device__ __forceinline__ void gw(const u32* f, u32 tok, int lane, bool fen) {
    while (true) {
        u32 v = (lane < GW)
            ? __hip_atomic_load(f + lane * 16, __ATOMIC_RELAXED,
                                __HIP_MEMORY_SCOPE_AGENT)
            : tok;
        if (__ballot(v == tok) == ~0ull) break;
        __builtin_amdgcn_s_sleep(1);
    }
    if (fen) __builtin_amdgcn_fence(__ATOMIC_ACQUIRE, "agent");
    else     asm volatile("" ::: "memory");
}

// producer: post token with an AGENT store (prompt agent visibility).
// FEN adds release-agent fence (L2 writeback) so plain data stores are
// LLC-visible before the flag (cross-XCD correctness).
__device__ __forceinline__ void post_flag(u32* slot, u32 tok, bool fen) {
    if (fen) __builtin_amdgcn_fence(__ATOMIC_RELEASE, "agent");
    __hip_atomic_store(slot, tok, __ATOMIC_RELAXED, __HIP_MEMORY_SCOPE_AGENT);
}

__global__ void convert_plain(const float* __restrict__ src,
                              __bf16* __restrict__ dst, int n4) {
    int i = blockIdx.x * blockDim.x + threadIdx.x;
    if (i >= n4) return;
    float4 v = reinterpret_cast<const float4*>(src)[i];
    bf16x4 o;
    o[0] = (__bf16)v.x; o[1] = (__bf16)v.y; o[2] = (__bf16)v.z; o[3] = (__bf16)v.w;
    reinterpret_cast<bf16x4*>(dst)[i] = o;
}

__global__ void convert_split(const float* __restrict__ src,
                              __bf16* __restrict__ hi, __bf16* __restrict__ lo,
                              int n4) {
    int i = blockIdx.x * blockDim.x + threadIdx.x;
    if (i >= n4) return;
    float4 v = reinterpret_cast<const float4*>(src)[i];
    float f[4] = {v.x, v.y, v.z, v.w};
    bf16x4 h, l;
#pragma unroll
    for (int e = 0; e < 4; ++e) {
        __bf16 hh = (__bf16)f[e];
        h[e] = hh;
        l[e] = (__bf16)(f[e] - (float)hh);
    }
    reinterpret_cast<bf16x4*>(hi)[i] = h;
    reinterpret_cast<bf16x4*>(lo)[i] = l;
}

__global__ void zero_u32(u32* __restrict__ p, int n) {
    int i = blockIdx.x * blockDim.x + threadIdx.x;
    if (i < n) p[i] = 0;
}

__global__ __launch_bounds__(512, 2)
void rnn_kernel(const float* __restrict__ x,
                const __bf16* __restrict__ Abf,
                const __bf16* __restrict__ Bhi, const __bf16* __restrict__ Blo,
                const __bf16* __restrict__ Chi, const __bf16* __restrict__ Clo,
                const __bf16* __restrict__ Dhi, const __bf16* __restrict__ Dlo,
                float* __restrict__ out,
                u32* __restrict__ flags,   // [32][NEV][8*16]
                u32* __restrict__ Xex,     // [2][32][16][256] packed row-pairs (hi)
                float* __restrict__ Hpart) {// [32][8][16][256] f32 partial h
    __shared__ __bf16 Xhi[BC][XPAD];
    __shared__ __bf16 Xlo3[BC][X3PAD];   // X3 lo, local staging only (64 k)
    __shared__ __bf16 u_hi[BC][UPAD];
    __shared__ __bf16 u_lo[BC][UPAD];
    __shared__ f32x4  red4[10][64];      // 0..3: bu / A-it ; 4..9: D-part
    __shared__ float  dsum[32][16];      // D@u rows [32*sub,+32)
    __shared__ int    s_nofence;

    const int tid  = threadIdx.x;
    const int wave = tid >> 6;
    const int lane = tid & 63;
    const int quad = lane >> 4;
    const int l16  = lane & 15;
    const int g    = blockIdx.x & 31;   // blocks {g, g+32k}: same XCD under %8 map
    const int sub  = blockIdx.x >> 5;   // 0..7
    const int R0   = sub * 64;
    const int H0   = sub * 32;
    const int b0   = g * BC;
    const int m    = wave & 3;
    const int kh   = wave >> 2;
    const int m2   = wave & 1;
    const int kh4  = wave >> 1;

    // ---- preload weight fragments ----
    bf16x8 aF[8], bFh[6], bFl[6], cFh[2][2], cFl[2][2], dFh[3], dFl[3];
    {
        const int arow = R0 + m * 16 + l16;
#pragma unroll
        for (int s = 0; s < 8; ++s)
            aF[s] = *reinterpret_cast<const bf16x8*>(
                &Abf[arow * NIMP + (kh * 8 + s) * 32 + quad * 8]);
#pragma unroll
        for (int s = 0; s < 6; ++s) {
            const int o = arow * PDIM + (kh * 6 + s) * 32 + quad * 8;
            bFh[s] = *reinterpret_cast<const bf16x8*>(&Bhi[o]);
            bFl[s] = *reinterpret_cast<const bf16x8*>(&Blo[o]);
        }
        // partial-h: wave w owns h-rows [32w, +32), K-slice = own X rows [R0,+64)
#pragma unroll
        for (int tl = 0; tl < 2; ++tl)
#pragma unroll
        for (int s = 0; s < 2; ++s) {
            const int o = (32 * wave + tl * 16 + l16) * NIMP + R0 + s * 32 + quad * 8;
            cFh[tl][s] = *reinterpret_cast<const bf16x8*>(&Chi[o]);
            cFl[tl][s] = *reinterpret_cast<const bf16x8*>(&Clo[o]);
        }
        const int hrow = H0 + m2 * 16 + l16;
#pragma unroll
        for (int s = 0; s < 3; ++s) {
            const int o = hrow * PDIM + (kh4 * 3 + s) * 32 + quad * 8;
            dFh[s] = *reinterpret_cast<const bf16x8*>(&Dhi[o]);
            dFl[s] = *reinterpret_cast<const bf16x8*>(&Dlo[o]);
        }
    }

    u32* const fg   = flags + g * (NEV * GW * 16);
    const int xcol  = tid >> 5;   // 0..15
    const int xseg  = tid & 31;   // 0..31

    // ---- init: runtime XCD-uniformity check (decides fenceless mode) ----
    {
        u32 myid = __builtin_amdgcn_s_getreg((31u << 11) | 20u); // hwreg(XCC_ID,0,32)
        if (tid == 0)
            __hip_atomic_store(fg + 3 * (GW * 16) + sub * 16, 0x100u | (myid & 0xffu),
                               __ATOMIC_RELAXED, __HIP_MEMORY_SCOPE_SYSTEM);
        if (wave == 0) {
            u32 v = 0x100u;
            while (true) {
                v = (lane < GW) ? ld32sys(fg + 3 * (GW * 16) + lane * 16) : 0x100u;
                if (__ballot((v & 0x100u) != 0u) == ~0ull) break;
                __builtin_amdgcn_s_sleep(8);
            }
            u32 ref = __shfl((int)v, 0);
            bool same = (lane < GW) ? (v == ref) : true;
            bool allsame = (__ballot(same) == ~0ull);
            u32 nb = 0;
            if (lane == 0) {
                const u32* ns = flags + (size_t)((g + 1) & 31) * (NEV * GW * 16)
                              + 3 * (GW * 16);
                while (((nb = ld32sys(ns)) & 0x100u) == 0u)
                    __builtin_amdgcn_s_sleep(8);
            }
            nb = (u32)__shfl((int)nb, 0);
            if (lane == 0)
                s_nofence = (allsame && ((nb & 0xffu) != (ref & 0xffu))) ? 1 : 0;
        }
        __syncthreads();
    }
    const bool FEN = (s_nofence == 0);   // wave-uniform

    // consumer-side: read 8 f32 partials via sc0 (L2), sum -> hv[8]
    auto read_h_sum = [&](float* hv) {
        const float* base = Hpart + ((size_t)(g * 8 * 16) + xcol) * 256 + xseg * 8;
        f32x4 a0, a1, b0v, b1v, c0, c1, d0v, d1v;
        ld8x16_sc0(base, base + 4096, base + 8192, base + 12288,
                   a0, a1, b0v, b1v, c0, c1, d0v, d1v);
        f32x4 sA = a0 + b0v + c0 + d0v;
        f32x4 sB = a1 + b1v + c1 + d1v;
        ld8x16_sc0(base + 16384, base + 20480, base + 24576, base + 28672,
                   a0, a1, b0v, b1v, c0, c1, d0v, d1v);
        sA += a0 + b0v + c0 + d0v;
        sB += a1 + b1v + c1 + d1v;
        hv[0] = sA[0]; hv[1] = sA[1]; hv[2] = sA[2]; hv[3] = sA[3];
        hv[4] = sB[0]; hv[5] = sB[1]; hv[6] = sB[2]; hv[7] = sB[3];
    };

    for (int t = 0; t < SEQ; ++t) {
        const u32 tok = (u32)(t + 1);
        // ---- stage x-part of u ----
        {
            const int p4 = xseg << 2;
            float4 v = *reinterpret_cast<const float4*>(
                &x[((size_t)(b0 + xcol) * SEQ + t) * IN_DIM + p4]);
            float f[4] = {v.x, v.y, v.z, v.w};
            bf16x4 h, l;
#pragma unroll
            for (int e = 0; e < 4; ++e) {
                __bf16 hh = (__bf16)f[e];
                h[e] = hh;
                l[e] = (__bf16)(f[e] - (float)hh);
            }
            *reinterpret_cast<bf16x4*>(&u_hi[xcol][p4]) = h;
            *reinterpret_cast<bf16x4*>(&u_lo[xcol][p4]) = l;
        }
        if (t == 0) {
            bf16x8 z = {};
            *reinterpret_cast<bf16x8*>(&u_hi[xcol][IN_DIM + xseg * 8]) = z;
            *reinterpret_cast<bf16x8*>(&u_lo[xcol][IN_DIM + xseg * 8]) = z;
        } else {
            if (wave == 0) gw(fg + 2 * (GW * 16), (u32)t, lane, FEN);
            __syncthreads();
            float hv[8];
            read_h_sum(hv);
            bf16x8 hh, hl;
#pragma unroll
            for (int e = 0; e < 8; ++e) {
                __bf16 q = (__bf16)hv[e];
                hh[e] = q;
                hl[e] = (__bf16)(hv[e] - (float)q);
            }
            *reinterpret_cast<bf16x8*>(&u_hi[xcol][IN_DIM + xseg * 8]) = hh;
            *reinterpret_cast<bf16x8*>(&u_lo[xcol][IN_DIM + xseg * 8]) = hl;
            if ((xseg >> 2) == sub) {
                float4 o0 = {hv[0], hv[1], hv[2], hv[3]};
                float4 o1 = {hv[4], hv[5], hv[6], hv[7]};
                size_t ob = ((size_t)(b0 + xcol) * SEQ + (t - 1)) * HID + xseg * 8;
                *reinterpret_cast<float4*>(&out[ob])     = o0;
                *reinterpret_cast<float4*>(&out[ob + 4]) = o1;
            }
        }
        __syncthreads();

        // ---- bu = Bmat @ u (split, K-halved across wave pairs) ----
        f32x4 acc = {0.f, 0.f, 0.f, 0.f};
#pragma unroll
        for (int s = 0; s < 6; ++s) {
            const int k0 = (kh * 6 + s) * 32 + quad * 8;
            bf16x8 uh = *reinterpret_cast<const bf16x8*>(&u_hi[l16][k0]);
            bf16x8 ul = *reinterpret_cast<const bf16x8*>(&u_lo[l16][k0]);
            acc = __builtin_amdgcn_mfma_f32_16x16x32_bf16(bFh[s], uh, acc, 0, 0, 0);
            acc = __builtin_amdgcn_mfma_f32_16x16x32_bf16(bFh[s], ul, acc, 0, 0, 0);
            acc = __builtin_amdgcn_mfma_f32_16x16x32_bf16(bFl[s], uh, acc, 0, 0, 0);
        }
        if (kh == 1) red4[m][lane] = acc;
        __syncthreads();
        f32x4 bu_acc = acc;
        if (kh == 0) bu_acc = acc + red4[m][lane];

        // ---- broadcast own X chunk, read back all 512 rows (R9 skeleton) ----
        auto xexchange = [&](int itx, const f32x4& tot) {
            const int buf = itx & 1;
            if (kh == 0) {
                float r0f = fmaxf(tot[0], 0.f), r1f = fmaxf(tot[1], 0.f);
                float r2f = fmaxf(tot[2], 0.f), r3f = fmaxf(tot[3], 0.f);
                u32 d0 = (u32)bfb(r0f) | ((u32)bfb(r1f) << 16);
                u32 d1 = (u32)bfb(r2f) | ((u32)bfb(r3f) << 16);
                const int rp = (R0 + m * 16 + quad * 4) >> 1;
                stp64(reinterpret_cast<u64*>(
                          Xex + (((size_t)buf * 32 + g) * 16 + l16) * 256 + rp),
                      ((u64)d1 << 32) | d0);
            }
            __syncthreads();  // every wave drains vmcnt(0) -> stores in L2
            {
                u32* f = fg + itx * (GW * 16);
                if (wave == 0) {
                    if (lane == 0) post_flag(f + sub * 16, tok, FEN);
                    gw(f, tok, lane, FEN);
                }
            }
            __syncthreads();
            {   // read back full X (hi) via sc0 (L2)
                const u32* src = Xex + (((size_t)buf * 32 + g) * 16 + xcol) * 256
                               + xseg * 4;
                u32x4 qa, qb;
                ld2x16_sc0(src, qa, qb);
                union { u32x4 q; bf16x8 v; } cA, cB;
                cA.q = qa; cB.q = qb;
                *reinterpret_cast<bf16x8*>(&Xhi[xcol][xseg * 8])       = cA.v;
                *reinterpret_cast<bf16x8*>(&Xhi[xcol][256 + xseg * 8]) = cB.v;
            }
            __syncthreads();
        };

        // ---- X1 = relu(bu), round 0 ----
        xexchange(0, bu_acc);

        // ---- it=2: X2 = relu(A @ X1 + bu), round 1 ----
        {
            f32x4 p;
            if (kh == 0) p = bu_acc;
            else { p[0] = 0.f; p[1] = 0.f; p[2] = 0.f; p[3] = 0.f; }
#pragma unroll
            for (int s = 0; s < 8; ++s) {
                const int k0 = (kh * 8 + s) * 32 + quad * 8;
                bf16x8 xF = *reinterpret_cast<const bf16x8*>(&Xhi[l16][k0]);
                p = __builtin_amdgcn_mfma_f32_16x16x32_bf16(aF[s], xF, p, 0, 0, 0);
            }
            if (kh == 1) red4[m][lane] = p;
            __syncthreads();
            f32x4 tot = p;
            if (kh == 0) tot = p + red4[m][lane];
            xexchange(1, tot);
        }

        // ---- it=3: X3 = relu(A @ X2 + bu) stays LOCAL (f32 -> hi/lo LDS) ----
        {
            f32x4 p;
            if (kh == 0) p = bu_acc;
            else { p[0] = 0.f; p[1] = 0.f; p[2] = 0.f; p[3] = 0.f; }
#pragma unroll
            for (int s = 0; s < 8; ++s) {
                const int k0 = (kh * 8 + s) * 32 + quad * 8;
                bf16x8 xF = *reinterpret_cast<const bf16x8*>(&Xhi[l16][k0]);
                p = __builtin_amdgcn_mfma_f32_16x16x32_bf16(aF[s], xF, p, 0, 0, 0);
            }
            if (kh == 1) red4[m][lane] = p;
            __syncthreads();                               // sync#1
            if (kh == 0) {
                f32x4 tot = p + red4[m][lane];
                bf16x4 xh, xl;
#pragma unroll
                for (int j = 0; j < 4; ++j) {
                    float r = fmaxf(tot[j], 0.f);
                    __bf16 hh = (__bf16)r;
                    xh[j] = hh;
                    xl[j] = (__bf16)(r - (float)hh);
                }
                *reinterpret_cast<bf16x4*>(&Xhi[l16][m * 16 + quad * 4])  = xh;
                *reinterpret_cast<bf16x4*>(&Xlo3[l16][m * 16 + quad * 4]) = xl;
            }
        }

        // ---- partial h: D@u (own 32 rows, K-quartered) + C_slice @ X3 ----
        {
            f32x4 hp = {0.f, 0.f, 0.f, 0.f};
#pragma unroll
            for (int s = 0; s < 3; ++s) {
                const int k0 = (kh4 * 3 + s) * 32 + quad * 8;
                bf16x8 uh = *reinterpret_cast<const bf16x8*>(&u_hi[l16][k0]);
                bf16x8 ul = *reinterpret_cast<const bf16x8*>(&u_lo[l16][k0]);
                hp = __builtin_amdgcn_mfma_f32_16x16x32_bf16(dFh[s], uh, hp, 0, 0, 0);
                hp = __builtin_amdgcn_mfma_f32_16x16x32_bf16(dFh[s], ul, hp, 0, 0, 0);
                hp = __builtin_amdgcn_mfma_f32_16x16x32_bf16(dFl[s], uh, hp, 0, 0, 0);
            }
            if (kh4 > 0) red4[4 + m2 * 3 + (kh4 - 1)][lane] = hp;
            __syncthreads();                               // sync#2 (X3 staged too)
            if (kh4 == 0) {
                f32x4 dt = hp + red4[4 + m2 * 3][lane] + red4[4 + m2 * 3 + 1][lane]
                              + red4[4 + m2 * 3 + 2][lane];
#pragma unroll
                for (int j = 0; j < 4; ++j)
                    dsum[m2 * 16 + quad * 4 + j][l16] = dt[j];
            }
            // C-part: wave w -> h-rows [32w,+32), K = own 64 X rows
            f32x4 ph0 = {0.f, 0.f, 0.f, 0.f}, ph1 = {0.f, 0.f, 0.f, 0.f};
#pragma unroll
            for (int s = 0; s < 2; ++s) {
                const int k0 = s * 32 + quad * 8;
                bf16x8 xh = *reinterpret_cast<const bf16x8*>(&Xhi[l16][k0]);
                bf16x8 xl = *reinterpret_cast<const bf16x8*>(&Xlo3[l16][k0]);
                ph0 = __builtin_amdgcn_mfma_f32_16x16x32_bf16(cFh[0][s], xh, ph0, 0, 0, 0);
                ph0 = __builtin_amdgcn_mfma_f32_16x16x32_bf16(cFh[0][s], xl, ph0, 0, 0, 0);
                ph0 = __builtin_amdgcn_mfma_f32_16x16x32_bf16(cFl[0][s], xh, ph0, 0, 0, 0);
                ph1 = __builtin_amdgcn_mfma_f32_16x16x32_bf16(cFh[1][s], xh, ph1, 0, 0, 0);
                ph1 = __builtin_amdgcn_mfma_f32_16x16x32_bf16(cFh[1][s], xl, ph1, 0, 0, 0);
                ph1 = __builtin_amdgcn_mfma_f32_16x16x32_bf16(cFl[1][s], xh, ph1, 0, 0, 0);
            }
            __syncthreads();                               // sync#3 (dsum visible)
            if (wave == sub) {
#pragma unroll
                for (int j = 0; j < 4; ++j) {
                    ph0[j] += dsum[quad * 4 + j][l16];
                    ph1[j] += dsum[16 + quad * 4 + j][l16];
                }
            }
            // store f32 partial: Hpart[g][sub][col l16][row 32*wave + ...]
            u64* hb = reinterpret_cast<u64*>(
                Hpart + (((size_t)g * 8 + sub) * 16 + l16) * 256
                      + 32 * wave + quad * 4);
            stp64(hb,     packf2(ph0[0], ph0[1]));
            stp64(hb + 1, packf2(ph0[2], ph0[3]));
            stp64(hb + 8, packf2(ph1[0], ph1[1]));
            stp64(hb + 9, packf2(ph1[2], ph1[3]));
        }
        __syncthreads();  // drain Hpart stores (vmcnt(0) per wave)
        if (tid == 0) post_flag(fg + 2 * (GW * 16) + sub * 16, tok, FEN);
        // waiters poll at the start of timestep t+1
    }

    // ---- tail: h(SEQ-1) -> out[SEQ-1] + h_last ----
    {
        if (wave == 0) gw(fg + 2 * (GW * 16), (u32)SEQ, lane, FEN);
        __syncthreads();
        float hv[8];
        read_h_sum(hv);
        if ((xseg >> 2) == sub) {
            float4 o0 = {hv[0], hv[1], hv[2], hv[3]};
            float4 o1 = {hv[4], hv[5], hv[6], hv[7]};
            size_t ob = ((size_t)(b0 + xcol) * SEQ + (SEQ - 1)) * HID + xseg * 8;
            *reinterpret_cast<float4*>(&out[ob])     = o0;
            *reinterpret_cast<float4*>(&out[ob + 4]) = o1;
            size_t hb2 = (size_t)B_SZ * SEQ * HID + (size_t)(b0 + xcol) * HID + xseg * 8;
            *reinterpret_cast<float4*>(&out[hb2])     = o0;
            *reinterpret_cast<float4*>(&out[hb2 + 4]) = o1;
        }
    }
}

extern "C" void kernel_launch(void* const* d_in, const int* in_sizes, int n_in,
                              void* d_out, int out_size, void* d_ws, size_t ws_size,
                              hipStream_t stream) {
    const float* x  = (const float*)d_in[0];
    const float* A  = (const float*)d_in[1];
    const float* Bm = (const float*)d_in[2];
    const float* C  = (const float*)d_in[3];
    const float* D  = (const float*)d_in[4];
    float* out = (float*)d_out;

    char* ws = (char*)d_ws;
    __bf16* Abf = (__bf16*)(ws);               // 524288
    __bf16* Bhi = (__bf16*)(ws + 524288);      // 393216
    __bf16* Blo = (__bf16*)(ws + 917504);
    __bf16* Chi = (__bf16*)(ws + 1310720);     // 262144
    __bf16* Clo = (__bf16*)(ws + 1572864);
    __bf16* Dhi = (__bf16*)(ws + 1835008);     // 196608
    __bf16* Dlo = (__bf16*)(ws + 2031616);
    u32* flags  = (u32*)(ws + 2228224);        // 32*4*8*16*4 = 65536
    u32* Xex    = (u32*)(ws + 2293760);        // 1048576
    float* Hpart= (float*)(ws + 3342336);      // 32*8*16*256*4 = 4194304 -> 7536640

    convert_plain<<<256, 256, 0, stream>>>(A, Abf, 262144 / 4);
    convert_split<<<192, 256, 0, stream>>>(Bm, Bhi, Blo, 196608 / 4);
    convert_split<<<128, 256, 0, stream>>>(C, Chi, Clo, 131072 / 4);
    convert_split<<<96, 256, 0, stream>>>(D, Dhi, Dlo, 98304 / 4);
    zero_u32<<<64, 256, 0, stream>>>(flags, 32 * NEV * GW * 16);

    rnn_kernel<<<256, 512, 0, stream>>>(x, Abf, Bhi, Blo, Chi, Clo, Dhi, Dlo,
                                        out, flags, Xex, Hpart);
}